// Round 6
// baseline (332.070 us; speedup 1.0000x reference)
//
#include <hip/hip_runtime.h>
#include <hip/hip_bf16.h>
#include <hip/hip_cooperative_groups.h>
#include <stdint.h>

namespace cg = cooperative_groups;

#define B_ 4
#define T_ 64
#define L_ 4096
#define D_ 4096

using bf8   = __attribute__((ext_vector_type(8))) short;   // 8 bf16 (4 VGPRs)
using f32x4 = __attribute__((ext_vector_type(4))) float;   // MFMA accumulator

// round-to-nearest-even fp32 -> bf16 (bit pattern in ushort)
__device__ __forceinline__ unsigned short f2bf(float f) {
    union { float f; unsigned int u; } v;
    v.f = f;
    unsigned int r = v.u + 0x7fffu + ((v.u >> 16) & 1u);
    return (unsigned short)(r >> 16);
}

// XOR swizzle on 16B chunks within a 128B LDS row; same fn on write & read.
__device__ __forceinline__ int swz16(int row, int byteoff) {
    return byteoff ^ (((row ^ (row >> 3)) & 7) << 4);
}

// MFMA fragment read from a [rows][64] bf16 tile (128B row stride).
__device__ __forceinline__ bf8 read_frag(const unsigned short* lds, int row, int kk, int lane) {
    int byte = kk * 64 + ((lane >> 4) << 4);
    int off  = row * 128 + swz16(row, byte);
    return *reinterpret_cast<const bf8*>(reinterpret_cast<const char*>(lds) + off);
}

// ==================== phase bodies (shared by fused + fallback kernels) ====================

__device__ __forceinline__ void phase_qprep(const float* __restrict__ Q,
                                            unsigned short* __restrict__ Qbf,
                                            int bid, int tid) {
    int i = bid * 256 + tid;                     // 65536 float4s == 256*256 exactly
    float4 f = reinterpret_cast<const float4*>(Q)[i];
    ushort4 u;
    u.x = f2bf(f.x); u.y = f2bf(f.y); u.z = f2bf(f.z); u.w = f2bf(f.w);
    reinterpret_cast<ushort4*>(Qbf)[i] = u;
}

// scores[b,t,l] = (Q[t,:] . mask[b,l,:]) / 64 ; tile 64(T) x 64(l), K-step 64, drain loop (R1-proven)
__device__ __forceinline__ void phase_scores(
    const float* __restrict__ mask, const unsigned short* __restrict__ Qbf,
    float* __restrict__ scores, int b, int l0, int tid,
    unsigned short (*lA)[64 * 64], unsigned short (*lB)[64 * 64]) {
    const int lane = tid & 63;
    const int wave = tid >> 6;
    const int wm = wave >> 1, wn = wave & 1;     // 2x2 waves, 32x32 out each
    const float* __restrict__ Mb = mask + (size_t)b * L_ * D_;

    f32x4 acc[2][2] = {};
    uint4  ra[2];    // Q slab:   64x64 bf16 = 8 KB
    float4 rb[4];    // mask slab:64x64 f32  = 16 KB

    auto loadTiles = [&](int k0) {
#pragma unroll
        for (int s = 0; s < 2; ++s) {
            int slot = tid + s * 256;            // 64 rows x 8 chunks
            int r = slot >> 3, c = slot & 7;
            ra[s] = *reinterpret_cast<const uint4*>(Qbf + (size_t)r * D_ + k0 + c * 8);
        }
#pragma unroll
        for (int s = 0; s < 4; ++s) {
            int slot = tid + s * 256;            // 64 rows x 16 float4
            int r = slot >> 4, c = slot & 15;
            rb[s] = *reinterpret_cast<const float4*>(Mb + (size_t)(l0 + r) * D_ + k0 + c * 4);
        }
    };
    auto writeTiles = [&](int buf) {
#pragma unroll
        for (int s = 0; s < 2; ++s) {
            int slot = tid + s * 256;
            int r = slot >> 3, c = slot & 7;
            int off = r * 128 + swz16(r, c * 16);
            *reinterpret_cast<uint4*>(reinterpret_cast<char*>(lA[buf]) + off) = ra[s];
        }
#pragma unroll
        for (int s = 0; s < 4; ++s) {
            int slot = tid + s * 256;
            int r = slot >> 4, c = slot & 15;
            int off = r * 128 + swz16(r, c * 8);
            ushort4 u;
            u.x = f2bf(rb[s].x); u.y = f2bf(rb[s].y); u.z = f2bf(rb[s].z); u.w = f2bf(rb[s].w);
            *reinterpret_cast<ushort4*>(reinterpret_cast<char*>(lB[buf]) + off) = u;
        }
    };

    loadTiles(0);
    writeTiles(0);
    __syncthreads();
    const int NT = D_ / 64;
    for (int kt = 0; kt < NT; ++kt) {
        int cur = kt & 1;
        if (kt + 1 < NT) loadTiles((kt + 1) * 64);
#pragma unroll
        for (int kk = 0; kk < 2; ++kk) {
            bf8 a0 = read_frag(lA[cur], wm * 32 +      (lane & 15), kk, lane);
            bf8 a1 = read_frag(lA[cur], wm * 32 + 16 + (lane & 15), kk, lane);
            bf8 b0 = read_frag(lB[cur], wn * 32 +      (lane & 15), kk, lane);
            bf8 b1 = read_frag(lB[cur], wn * 32 + 16 + (lane & 15), kk, lane);
            acc[0][0] = __builtin_amdgcn_mfma_f32_16x16x32_bf16(a0, b0, acc[0][0], 0, 0, 0);
            acc[0][1] = __builtin_amdgcn_mfma_f32_16x16x32_bf16(a0, b1, acc[0][1], 0, 0, 0);
            acc[1][0] = __builtin_amdgcn_mfma_f32_16x16x32_bf16(a1, b0, acc[1][0], 0, 0, 0);
            acc[1][1] = __builtin_amdgcn_mfma_f32_16x16x32_bf16(a1, b1, acc[1][1], 0, 0, 0);
        }
        if (kt + 1 < NT) writeTiles(cur ^ 1);
        __syncthreads();
    }

    const int rgrp = (lane >> 4) * 4;
    const int cidx = lane & 15;
#pragma unroll
    for (int mi = 0; mi < 2; ++mi)
#pragma unroll
        for (int nj = 0; nj < 2; ++nj)
#pragma unroll
            for (int r = 0; r < 4; ++r) {
                int t = wm * 32 + mi * 16 + rgrp + r;
                int l = l0 + wn * 32 + nj * 16 + cidx;
                scores[((size_t)b * T_ + t) * L_ + l] = acc[mi][nj][r] * 0.015625f;
            }
}

__device__ __forceinline__ void phase_softmax(
    const float* __restrict__ scores, const int* __restrict__ am,
    unsigned short* __restrict__ attn, int row, int tid) {
    const int lane = tid & 63;
    const int wave = tid >> 6;
    const float* __restrict__ s = scores + (size_t)row * L_;
    const int*   __restrict__ m = am     + (size_t)row * L_;
    __shared__ float redmax[4], redsum[4];

    float v[16];
#pragma unroll
    for (int j = 0; j < 4; ++j) {
        float4 f = *(reinterpret_cast<const float4*>(s) + tid + j * 256);
        int4   q = *(reinterpret_cast<const int4*>(m)   + tid + j * 256);
        v[j * 4 + 0] = q.x ? -1.0e9f : f.x;
        v[j * 4 + 1] = q.y ? -1.0e9f : f.y;
        v[j * 4 + 2] = q.z ? -1.0e9f : f.z;
        v[j * 4 + 3] = q.w ? -1.0e9f : f.w;
    }
    float mx = -3.0e38f;
#pragma unroll
    for (int i = 0; i < 16; ++i) mx = fmaxf(mx, v[i]);
#pragma unroll
    for (int off = 32; off; off >>= 1) mx = fmaxf(mx, __shfl_xor(mx, off, 64));
    if (lane == 0) redmax[wave] = mx;
    __syncthreads();
    mx = fmaxf(fmaxf(redmax[0], redmax[1]), fmaxf(redmax[2], redmax[3]));

    float z = 0.f;
#pragma unroll
    for (int i = 0; i < 16; ++i) {
        v[i] = exp2f((v[i] - mx) * 1.4426950408889634f);
        z += v[i];
    }
#pragma unroll
    for (int off = 32; off; off >>= 1) z += __shfl_xor(z, off, 64);
    if (lane == 0) redsum[wave] = z;
    __syncthreads();
    z = (redsum[0] + redsum[1]) + (redsum[2] + redsum[3]);
    float inv = 1.0f / z;

    unsigned short* __restrict__ arow = attn + (size_t)row * L_;
#pragma unroll
    for (int j = 0; j < 4; ++j) {
        ushort4 u;
        u.x = f2bf(v[j * 4 + 0] * inv);
        u.y = f2bf(v[j * 4 + 1] * inv);
        u.z = f2bf(v[j * 4 + 2] * inv);
        u.w = f2bf(v[j * 4 + 3] * inv);
        *(reinterpret_cast<ushort4*>(arow) + tid + j * 256) = u;
    }
}

// context[b,t,d] = sum_l attn[b,t,l] * mask[b,l,d] ; mask tile staged TRANSPOSED [d][l]
__device__ __forceinline__ void phase_context(
    const float* __restrict__ mask, const unsigned short* __restrict__ attn,
    float* __restrict__ out, int b, int d0, int tid,
    unsigned short (*lA)[64 * 64], unsigned short (*lB)[64 * 64]) {
    const int lane = tid & 63;
    const int wave = tid >> 6;
    const int wm = wave >> 1, wn = wave & 1;
    const float*          __restrict__ Mb = mask + (size_t)b * L_ * D_;
    const unsigned short* __restrict__ Ab = attn + (size_t)b * T_ * L_;

    f32x4 acc[2][2] = {};
    uint4  ra[2];    // attn slab: 64 t x 64 l bf16 = 8 KB
    float4 rb[4];    // mask slab: 64 l x 64 d f32  = 16 KB

    auto loadTiles = [&](int k0) {
#pragma unroll
        for (int s = 0; s < 2; ++s) {
            int slot = tid + s * 256;
            int r = slot >> 3, c = slot & 7;
            ra[s] = *reinterpret_cast<const uint4*>(Ab + (size_t)r * L_ + k0 + c * 8);
        }
#pragma unroll
        for (int s = 0; s < 4; ++s) {
            int slot = tid + s * 256;
            int kl = slot >> 4, c = slot & 15;
            rb[s] = *reinterpret_cast<const float4*>(Mb + (size_t)(k0 + kl) * D_ + d0 + c * 4);
        }
    };
    auto writeTiles = [&](int buf) {
#pragma unroll
        for (int s = 0; s < 2; ++s) {
            int slot = tid + s * 256;
            int r = slot >> 3, c = slot & 7;
            int off = r * 128 + swz16(r, c * 16);
            *reinterpret_cast<uint4*>(reinterpret_cast<char*>(lA[buf]) + off) = ra[s];
        }
#pragma unroll
        for (int s = 0; s < 4; ++s) {
            int slot = tid + s * 256;
            int kl = slot >> 4, c = slot & 15;
            float fv[4] = { rb[s].x, rb[s].y, rb[s].z, rb[s].w };
#pragma unroll
            for (int i = 0; i < 4; ++i) {
                int d = c * 4 + i;
                int off = d * 128 + swz16(d, kl * 2);   // transposed scalar b16 store
                *reinterpret_cast<unsigned short*>(reinterpret_cast<char*>(lB[buf]) + off) = f2bf(fv[i]);
            }
        }
    };

    loadTiles(0);
    writeTiles(0);
    __syncthreads();
    const int NT = L_ / 64;
    for (int kt = 0; kt < NT; ++kt) {
        int cur = kt & 1;
        if (kt + 1 < NT) loadTiles((kt + 1) * 64);
#pragma unroll
        for (int kk = 0; kk < 2; ++kk) {
            bf8 a0 = read_frag(lA[cur], wm * 32 +      (lane & 15), kk, lane);
            bf8 a1 = read_frag(lA[cur], wm * 32 + 16 + (lane & 15), kk, lane);
            bf8 b0 = read_frag(lB[cur], wn * 32 +      (lane & 15), kk, lane);
            bf8 b1 = read_frag(lB[cur], wn * 32 + 16 + (lane & 15), kk, lane);
            acc[0][0] = __builtin_amdgcn_mfma_f32_16x16x32_bf16(a0, b0, acc[0][0], 0, 0, 0);
            acc[0][1] = __builtin_amdgcn_mfma_f32_16x16x32_bf16(a0, b1, acc[0][1], 0, 0, 0);
            acc[1][0] = __builtin_amdgcn_mfma_f32_16x16x32_bf16(a1, b0, acc[1][0], 0, 0, 0);
            acc[1][1] = __builtin_amdgcn_mfma_f32_16x16x32_bf16(a1, b1, acc[1][1], 0, 0, 0);
        }
        if (kt + 1 < NT) writeTiles(cur ^ 1);
        __syncthreads();
    }

    const int rgrp = (lane >> 4) * 4;
    const int cidx = lane & 15;
#pragma unroll
    for (int mi = 0; mi < 2; ++mi)
#pragma unroll
        for (int nj = 0; nj < 2; ++nj)
#pragma unroll
            for (int r = 0; r < 4; ++r) {
                int t = wm * 32 + mi * 16 + rgrp + r;
                int d = d0 + wn * 32 + nj * 16 + cidx;
                out[((size_t)b * T_ + t) * D_ + d] = acc[mi][nj][r];
            }
}

// ==================== fused cooperative kernel ====================
__global__ __launch_bounds__(256, 1) void k_fused(
    const float* __restrict__ mask, const float* __restrict__ Q,
    const int* __restrict__ am, float* __restrict__ out,
    unsigned short* __restrict__ attn, unsigned short* __restrict__ Qbf,
    float* __restrict__ scores) {
    __shared__ unsigned short lA[2][64 * 64];
    __shared__ unsigned short lB[2][64 * 64];
    cg::grid_group grid = cg::this_grid();
    const int bid = blockIdx.x;
    const int tid = threadIdx.x;

    phase_qprep(Q, Qbf, bid, tid);
    grid.sync();
    phase_scores(mask, Qbf, scores, bid >> 6, (bid & 63) * 64, tid, lA, lB);
    grid.sync();
    phase_softmax(scores, am, attn, bid, tid);
    grid.sync();
    phase_context(mask, attn, out, bid >> 6, (bid & 63) * 64, tid, lA, lB);
}

// ==================== fallback standalone kernels (identical math) ====================
__global__ __launch_bounds__(256) void k_qprep(const float* __restrict__ Q,
                                               unsigned short* __restrict__ Qbf) {
    phase_qprep(Q, Qbf, blockIdx.x, threadIdx.x);
}
__global__ __launch_bounds__(256, 1) void k_scores(const float* __restrict__ mask,
                                                   const unsigned short* __restrict__ Qbf,
                                                   float* __restrict__ scores) {
    __shared__ unsigned short lA[2][64 * 64];
    __shared__ unsigned short lB[2][64 * 64];
    phase_scores(mask, Qbf, scores, blockIdx.y, blockIdx.x * 64, threadIdx.x, lA, lB);
}
__global__ __launch_bounds__(256, 4) void k_softmax(const float* __restrict__ scores,
                                                    const int* __restrict__ am,
                                                    unsigned short* __restrict__ attn) {
    phase_softmax(scores, am, attn, blockIdx.x, threadIdx.x);
}
__global__ __launch_bounds__(256, 1) void k_context(const float* __restrict__ mask,
                                                    const unsigned short* __restrict__ attn,
                                                    float* __restrict__ out) {
    __shared__ unsigned short lA[2][64 * 64];
    __shared__ unsigned short lB[2][64 * 64];
    phase_context(mask, attn, out, blockIdx.y, blockIdx.x * 64, threadIdx.x, lA, lB);
}

extern "C" void kernel_launch(void* const* d_in, const int* in_sizes, int n_in,
                              void* d_out, int out_size, void* d_ws, size_t ws_size,
                              hipStream_t stream) {
    const float* mask = (const float*)d_in[0];        // [B, L, D] fp32
    const float* Q    = (const float*)d_in[1];        // [1, T, D] fp32
    const int*   am   = (const int*)d_in[2];          // [B, T, L] int (bool)
    float* out = (float*)d_out;                       // [B, T, D] fp32

    unsigned short* attn = (unsigned short*)d_ws;                           // 2 MB bf16
    unsigned short* Qbf  = (unsigned short*)((char*)d_ws + (2u << 20));     // 512 KB
    float*          scrs = (float*)((char*)d_ws + (2u << 20) + (512u << 10)); // 4 MB

    void* args[] = { (void*)&mask, (void*)&Q, (void*)&am, (void*)&out,
                     (void*)&attn, (void*)&Qbf, (void*)&scrs };
    hipError_t e = hipLaunchCooperativeKernel((const void*)k_fused, dim3(256), dim3(256),
                                              args, 0, stream);
    if (e != hipSuccess) {
        // Fallback: identical math as four plain launches.
        k_qprep<<<dim3(T_ * D_ / 4 / 256), 256, 0, stream>>>(Q, Qbf);
        k_scores<<<dim3(L_ / 64, B_), 256, 0, stream>>>(mask, Qbf, scrs);
        k_softmax<<<dim3(B_ * T_), 256, 0, stream>>>(scrs, am, attn);
        k_context<<<dim3(D_ / 64, B_), 256, 0, stream>>>(mask, attn, out);
    }
}

// Round 7
// 219.909 us; speedup vs baseline: 1.5100x; 1.5100x over previous
//
#include <hip/hip_runtime.h>
#include <hip/hip_bf16.h>
#include <stdint.h>

#define B_ 4
#define T_ 64
#define L_ 4096
#define D_ 4096

using bf8   = __attribute__((ext_vector_type(8))) short;   // 8 bf16 (4 VGPRs)
using f32x4 = __attribute__((ext_vector_type(4))) float;   // MFMA accumulator

// round-to-nearest-even fp32 -> bf16 (bit pattern in ushort) — scalar paths
__device__ __forceinline__ unsigned short f2bf(float f) {
    union { float f; unsigned int u; } v;
    v.f = f;
    unsigned int r = v.u + 0x7fffu + ((v.u >> 16) & 1u);
    return (unsigned short)(r >> 16);
}

// HW packed f32->bf16 RNE (no builtin on gfx950; inline asm per guide T12)
__device__ __forceinline__ unsigned int cvt_pk(float lo, float hi) {
    unsigned int r;
    asm("v_cvt_pk_bf16_f32 %0, %1, %2" : "=v"(r) : "v"(lo), "v"(hi));
    return r;
}

union BF8U { bf8 v; unsigned int u[4]; };

// ---------------- Kernel 0: Q fp32 -> bf16 once ----------------
__global__ __launch_bounds__(256) void k_qprep(const float* __restrict__ Q,
                                               unsigned short* __restrict__ Qbf) {
    int i = blockIdx.x * 256 + threadIdx.x;          // 65536 float4s
    float4 f = reinterpret_cast<const float4*>(Q)[i];
    ushort4 u;
    u.x = f2bf(f.x); u.y = f2bf(f.y); u.z = f2bf(f.z); u.w = f2bf(f.w);
    reinterpret_cast<ushort4*>(Qbf)[i] = u;
}

// ==================== Kernel 1: scores = Q . mask^T / 64 ====================
// Barrier-free, LDS-free. 2048 waves (512 blocks x 4), 8 waves/CU.
// Each wave: out tile 32(T) x 16(l). B-fragment loaded straight from mask rows
// (K-contiguous float4 pairs), A-fragment straight from Qbf. Compiler pipelines.
__global__ __launch_bounds__(256, 2) void k_scores(
    const float* __restrict__ mask, const unsigned short* __restrict__ Qbf,
    float* __restrict__ scores) {
    const int tid  = threadIdx.x;
    const int lane = tid & 63;
    const int w    = blockIdx.x * 4 + (tid >> 6);
    const int lt = w & 255;          // l-tile (16 wide)
    const int b  = (w >> 8) & 3;
    const int th = w >> 10;          // t-half (0/1)
    const int l0 = lt * 16, t0 = th * 32;
    const int lr = lane & 15, hi = lane >> 4;

    const float* __restrict__ Mb = mask + (size_t)b * L_ * D_;
    const float* __restrict__ pB = Mb + (size_t)(l0 + lr) * D_ + hi * 8;
    const unsigned short* __restrict__ pA0 = Qbf + (size_t)(t0 + lr) * D_ + hi * 8;
    const unsigned short* __restrict__ pA1 = pA0 + 16 * D_;

    f32x4 acc0 = {}, acc1 = {};
#pragma unroll 4
    for (int k0 = 0; k0 < D_; k0 += 32) {
        float4 f0 = *reinterpret_cast<const float4*>(pB + k0);
        float4 f1 = *reinterpret_cast<const float4*>(pB + k0 + 4);
        bf8 a0 = *reinterpret_cast<const bf8*>(pA0 + k0);
        bf8 a1 = *reinterpret_cast<const bf8*>(pA1 + k0);
        BF8U bb;
        bb.u[0] = cvt_pk(f0.x, f0.y);
        bb.u[1] = cvt_pk(f0.z, f0.w);
        bb.u[2] = cvt_pk(f1.x, f1.y);
        bb.u[3] = cvt_pk(f1.z, f1.w);
        acc0 = __builtin_amdgcn_mfma_f32_16x16x32_bf16(a0, bb.v, acc0, 0, 0, 0);
        acc1 = __builtin_amdgcn_mfma_f32_16x16x32_bf16(a1, bb.v, acc1, 0, 0, 0);
    }

    // C/D layout: col = lane&15, row = (lane>>4)*4 + reg  (m89-verified)
    float* __restrict__ srow = scores + ((size_t)b * T_ + t0) * L_ + l0 + lr;
#pragma unroll
    for (int r = 0; r < 4; ++r) {
        srow[(size_t)(hi * 4 + r) * L_]        = acc0[r] * 0.015625f;  // 1/sqrt(4096)
        srow[(size_t)(16 + hi * 4 + r) * L_]   = acc1[r] * 0.015625f;
    }
}

// ---------------- Kernel 2: masked softmax over L, fp32 scores -> bf16 attn ----------------
__global__ __launch_bounds__(256, 4) void k_softmax(
    const float* __restrict__ scores, const int* __restrict__ am,
    unsigned short* __restrict__ attn) {
    const int row  = blockIdx.x;                 // b*T + t
    const int tid  = threadIdx.x;
    const int lane = tid & 63;
    const int wave = tid >> 6;
    const float* __restrict__ s = scores + (size_t)row * L_;
    const int*   __restrict__ m = am     + (size_t)row * L_;
    __shared__ float redmax[4], redsum[4];

    float v[16];
#pragma unroll
    for (int j = 0; j < 4; ++j) {
        float4 f = *(reinterpret_cast<const float4*>(s) + tid + j * 256);
        int4   q = *(reinterpret_cast<const int4*>(m)   + tid + j * 256);
        v[j * 4 + 0] = q.x ? -1.0e9f : f.x;
        v[j * 4 + 1] = q.y ? -1.0e9f : f.y;
        v[j * 4 + 2] = q.z ? -1.0e9f : f.z;
        v[j * 4 + 3] = q.w ? -1.0e9f : f.w;
    }
    float mx = -3.0e38f;
#pragma unroll
    for (int i = 0; i < 16; ++i) mx = fmaxf(mx, v[i]);
#pragma unroll
    for (int off = 32; off; off >>= 1) mx = fmaxf(mx, __shfl_xor(mx, off, 64));
    if (lane == 0) redmax[wave] = mx;
    __syncthreads();
    mx = fmaxf(fmaxf(redmax[0], redmax[1]), fmaxf(redmax[2], redmax[3]));

    float z = 0.f;
#pragma unroll
    for (int i = 0; i < 16; ++i) {
        v[i] = exp2f((v[i] - mx) * 1.4426950408889634f);
        z += v[i];
    }
#pragma unroll
    for (int off = 32; off; off >>= 1) z += __shfl_xor(z, off, 64);
    if (lane == 0) redsum[wave] = z;
    __syncthreads();
    z = (redsum[0] + redsum[1]) + (redsum[2] + redsum[3]);
    float inv = 1.0f / z;

    unsigned short* __restrict__ arow = attn + (size_t)row * L_;
#pragma unroll
    for (int j = 0; j < 4; ++j) {
        ushort4 u;
        u.x = f2bf(v[j * 4 + 0] * inv);
        u.y = f2bf(v[j * 4 + 1] * inv);
        u.z = f2bf(v[j * 4 + 2] * inv);
        u.w = f2bf(v[j * 4 + 3] * inv);
        *(reinterpret_cast<ushort4*>(arow) + tid + j * 256) = u;
    }
}

// ==================== Kernel 3: context = attn @ mask ====================
// Barrier-free, LDS-free. 2048 waves, 8 waves/CU. Out tile 32(T) x 16(d).
// B-fragment: 8 strided dword loads (each instr = 4 x 64B lines, mask L3-warm),
// packed to bf16 in regs. A-fragment straight from bf16 attn.
__global__ __launch_bounds__(256, 2) void k_context(
    const float* __restrict__ mask, const unsigned short* __restrict__ attn,
    float* __restrict__ out) {
    const int tid  = threadIdx.x;
    const int lane = tid & 63;
    const int w    = blockIdx.x * 4 + (tid >> 6);
    const int dt = w & 255;          // d-tile (16 wide)
    const int b  = (w >> 8) & 3;
    const int th = w >> 10;          // t-half
    const int d0 = dt * 16, t0 = th * 32;
    const int lr = lane & 15, hi = lane >> 4;

    const float*          __restrict__ Mb = mask + (size_t)b * L_ * D_;
    const unsigned short* __restrict__ Ab = attn + (size_t)b * T_ * L_;
    const unsigned short* __restrict__ pA0 = Ab + (size_t)(t0 + lr) * L_ + hi * 8;
    const unsigned short* __restrict__ pA1 = pA0 + 16 * L_;
    const float* __restrict__ pB = Mb + (size_t)(hi * 8) * D_ + d0 + lr;

    f32x4 acc0 = {}, acc1 = {};
#pragma unroll 2
    for (int k0 = 0; k0 < L_; k0 += 32) {
        const float* __restrict__ pb = pB + (size_t)k0 * D_;
        float b0 = pb[0 * D_], b1 = pb[1 * D_], b2 = pb[2 * D_], b3 = pb[3 * D_];
        float b4 = pb[4 * D_], b5 = pb[5 * D_], b6 = pb[6 * D_], b7 = pb[7 * D_];
        bf8 a0 = *reinterpret_cast<const bf8*>(pA0 + k0);
        bf8 a1 = *reinterpret_cast<const bf8*>(pA1 + k0);
        BF8U bb;
        bb.u[0] = cvt_pk(b0, b1);
        bb.u[1] = cvt_pk(b2, b3);
        bb.u[2] = cvt_pk(b4, b5);
        bb.u[3] = cvt_pk(b6, b7);
        acc0 = __builtin_amdgcn_mfma_f32_16x16x32_bf16(a0, bb.v, acc0, 0, 0, 0);
        acc1 = __builtin_amdgcn_mfma_f32_16x16x32_bf16(a1, bb.v, acc1, 0, 0, 0);
    }

    float* __restrict__ orow = out + ((size_t)b * T_ + t0) * D_ + d0 + lr;
#pragma unroll
    for (int r = 0; r < 4; ++r) {
        orow[(size_t)(hi * 4 + r) * D_]      = acc0[r];
        orow[(size_t)(16 + hi * 4 + r) * D_] = acc1[r];
    }
}

extern "C" void kernel_launch(void* const* d_in, const int* in_sizes, int n_in,
                              void* d_out, int out_size, void* d_ws, size_t ws_size,
                              hipStream_t stream) {
    const float* mask = (const float*)d_in[0];        // [B, L, D] fp32
    const float* Q    = (const float*)d_in[1];        // [1, T, D] fp32
    const int*   am   = (const int*)d_in[2];          // [B, T, L] int (bool)
    float* out = (float*)d_out;                       // [B, T, D] fp32

    unsigned short* attn = (unsigned short*)d_ws;                             // 2 MB bf16
    unsigned short* Qbf  = (unsigned short*)((char*)d_ws + (2u << 20));       // 512 KB
    float*          scrs = (float*)((char*)d_ws + (2u << 20) + (512u << 10)); // 4 MB

    k_qprep<<<dim3(T_ * D_ / 4 / 256), 256, 0, stream>>>(Q, Qbf);
    k_scores<<<dim3(512), 256, 0, stream>>>(mask, Qbf, scrs);
    k_softmax<<<dim3(B_ * T_), 256, 0, stream>>>(scrs, am, attn);
    k_context<<<dim3(512), 256, 0, stream>>>(mask, attn, out);
}